// Round 17
// baseline (152.567 us; speedup 1.0000x reference)
//
#include <hip/hip_runtime.h>

// Fused single-pass 3x3 VALID conv via bf16 MFMA implicit GEMM.
// x:(16,2048,2048) fp32, k:(16,16,3,3) fp32 -> out:(16,2046,2046) fp32
// 1024-thread blocks; each thread does AT MOST ONE stage task. The 8 plane-
// strided f32x4 loads are issued via inline-asm global_load_dwordx4 with
// early-clobber outputs so ALL EIGHT are in flight before a single
// s_waitcnt vmcnt(0) (the compiler otherwise serializes them at ~28 VGPRs —
// observed every round). Then 16 pk2 -> 4x ds_write_b128 (XOR-swizzled),
// and 5x mfma_16x16x32_bf16 per 16x16 sub-tile (verified contract).
// Weight fragments precomputed once into d_ws.

#define HIN   2048
#define WIN   2048
#define HOUT  2046
#define WOUT  2046
#define PLANE_IN  (HIN * WIN)
#define PLANE_OUT (HOUT * WOUT)
#define TR 34
#define TC 36                          // padded staging stride (cols)
#define NQTASK (TR * 9 * 2)            // 612: 34 rows x 9 w-quads x 2 ci-halves
#define WF_U32 (5 * 64 * 4)            // weight-frag buffer (5 KiB)

typedef __attribute__((ext_vector_type(8))) short bf16x8;
typedef __attribute__((ext_vector_type(4))) float f32x4;
typedef __attribute__((ext_vector_type(4))) unsigned u32x4;
typedef f32x4 __attribute__((aligned(4))) f32x4_u;

static __device__ __forceinline__ short f2bf(float f) {
    unsigned u = __float_as_uint(f);
    return (short)((u + 0x7FFFu + ((u >> 16) & 1u)) >> 16);   // RNE
}
static __device__ __forceinline__ unsigned pk2(float lo, float hi) {
    unsigned a = __float_as_uint(lo);
    unsigned b = __float_as_uint(hi);
    a = (a + 0x7FFFu + ((a >> 16) & 1u)) >> 16;
    b = (b + 0x7FFFu + ((b >> 16) & 1u)) & 0xFFFF0000u;
    return a | b;
}

// ---------------- setup: per-lane MFMA weight fragments ----------------------
__global__ __launch_bounds__(64)
void wf_setup(const float* __restrict__ k, unsigned* __restrict__ wfbuf) {
    int lane = threadIdx.x;
    int m = lane & 15, g = lane >> 4;
    #pragma unroll
    for (int i = 0; i < 5; ++i) {
        u32x4 q;
        #pragma unroll
        for (int jj = 0; jj < 4; ++jj) {
            unsigned r = 0;
            #pragma unroll
            for (int e = 0; e < 2; ++e) {
                int kk  = 32 * i + 8 * g + 2 * jj + e;
                int tap = kk >> 4;
                int ci  = kk & 15;
                unsigned v = 0;
                if (tap < 9) v = (unsigned short)f2bf(k[(m * 16 + ci) * 9 + tap]);
                r |= v << (16 * e);
            }
            q[jj] = r;
        }
        *(u32x4*)(wfbuf + (i * 64 + lane) * 4) = q;
    }
}

// asm load: forces a distinct live 4-VGPR destination per load
#define GLOADX4(DST, ADDR) \
    asm volatile("global_load_dwordx4 %0, %1, off" : "=&v"(DST) : "v"(ADDR))

// ---------------- primary: 1024-thread fused conv, asm-MLP staging -----------
__global__ __launch_bounds__(1024, 2)
void conv3x3_fused1k(const float* __restrict__ x,
                     const unsigned* __restrict__ wfbuf,
                     float* __restrict__ out) {
    __shared__ unsigned lds[TR * TC * 8];   // 39168 B

    const int tid  = threadIdx.x;
    const int lane = tid & 63;
    const int wv   = tid >> 6;              // 0..15
    const int m    = lane & 15;
    const int g    = lane >> 4;

    int bid = blockIdx.x;                      // 4096 blocks (64 x 64 tiles)
    int swz = (bid & 7) * 512 + (bid >> 3);    // XCD-chunked (4096 % 8 == 0)
    int h0 = (swz >> 6) * 32; if (h0 > HOUT - 32) h0 = HOUT - 32;  // 2014
    int w0 = (swz & 63) * 32;

    // ---- stage: ONE task/thread; 8 loads forced in flight via asm ----
    if (tid < NQTASK) {
        int t   = tid;
        int q   = t % 9;
        int r2  = t / 9;
        int cih = r2 & 1;
        int row = r2 >> 1;
        int c   = 4 * q;
        int w   = w0 + c; if (w > WIN - 4) w = WIN - 4;
        const float* gp = x + (size_t)(cih * 8) * PLANE_IN
                            + (size_t)(h0 + row) * WIN + w;
        f32x4 f0, f1, f2, f3, f4, f5, f6, f7;
        GLOADX4(f0, gp + 0 * (size_t)PLANE_IN);
        GLOADX4(f1, gp + 1 * (size_t)PLANE_IN);
        GLOADX4(f2, gp + 2 * (size_t)PLANE_IN);
        GLOADX4(f3, gp + 3 * (size_t)PLANE_IN);
        GLOADX4(f4, gp + 4 * (size_t)PLANE_IN);
        GLOADX4(f5, gp + 5 * (size_t)PLANE_IN);
        GLOADX4(f6, gp + 6 * (size_t)PLANE_IN);
        GLOADX4(f7, gp + 7 * (size_t)PLANE_IN);
        asm volatile("s_waitcnt vmcnt(0)" ::: "memory");
        __builtin_amdgcn_sched_barrier(0);      // rule 18: pin packs after wait

        int a = ((row * TC + c) * 32 + cih * 16) ^ ((c & 4) << 2);
        u32x4 ch;
        ch[0] = pk2(f0[0], f1[0]); ch[1] = pk2(f2[0], f3[0]);
        ch[2] = pk2(f4[0], f5[0]); ch[3] = pk2(f6[0], f7[0]);
        *(u32x4*)((char*)lds + a)      = ch;
        ch[0] = pk2(f0[1], f1[1]); ch[1] = pk2(f2[1], f3[1]);
        ch[2] = pk2(f4[1], f5[1]); ch[3] = pk2(f6[1], f7[1]);
        *(u32x4*)((char*)lds + a + 32) = ch;
        ch[0] = pk2(f0[2], f1[2]); ch[1] = pk2(f2[2], f3[2]);
        ch[2] = pk2(f4[2], f5[2]); ch[3] = pk2(f6[2], f7[2]);
        *(u32x4*)((char*)lds + a + 64) = ch;
        ch[0] = pk2(f0[3], f1[3]); ch[1] = pk2(f2[3], f3[3]);
        ch[2] = pk2(f4[3], f5[3]); ch[3] = pk2(f6[3], f7[3]);
        *(u32x4*)((char*)lds + a + 96) = ch;
    }

    // ---- weight fragments: 5 coalesced 16B loads (L2-hot) ----
    bf16x8 wf[5];
    #pragma unroll
    for (int i = 0; i < 5; ++i)
        wf[i] = *(const bf16x8*)(wfbuf + (i * 64 + lane) * 4);

    // ---- per-lane A-fragment LDS byte offsets ----
    int off[5];
    #pragma unroll
    for (int i = 0; i < 5; ++i) {
        int tap = 2 * i + (g >> 1);
        if (tap > 8) tap = 8;                   // dead K (weights are 0)
        int kh = tap / 3;
        int kw = tap - kh * 3;
        int col = m + kw;
        int o = (kh * TC + col) * 32 + (g & 1) * 16;
        off[i] = o ^ ((col & 4) << 2);          // matches staging swizzle
    }

    __syncthreads();

    const char* ldsb = (const char*)lds;

    #pragma unroll
    for (int hl2 = 0; hl2 < 2; ++hl2) {
        int hl = wv * 2 + hl2;                  // 16 waves x 2 rows = 32 rows
        int h  = h0 + hl;                       // always < HOUT (h0 <= 2014)
        #pragma unroll
        for (int nh = 0; nh < 2; ++nh) {
            int wl = nh * 16;
            int tb = (hl * TC + wl) * 32;
            f32x4 acc = {0.f, 0.f, 0.f, 0.f};
            #pragma unroll
            for (int i = 0; i < 5; ++i) {
                bf16x8 a = *(const bf16x8*)(ldsb + (tb + off[i]));
                acc = __builtin_amdgcn_mfma_f32_16x16x32_bf16(a, wf[i], acc, 0, 0, 0);
            }
            // D: row = g*4+r = spatial, col = m = co  ->  float4 store
            int w = w0 + wl + g * 4;
            float* op = out + m * (size_t)PLANE_OUT + (size_t)h * WOUT + w;
            if (w + 3 < WOUT) {
                *(f32x4_u*)op = acc;
            } else {
                #pragma unroll
                for (int r = 0; r < 4; ++r)
                    if (w + r < WOUT) op[r] = acc[r];
            }
        }
    }
}

// ---------------- fallback (no workspace): fp32-staged single pass -----------
__global__ __launch_bounds__(256, 4)
void conv3x3_mfma(const float* __restrict__ x,
                  const float* __restrict__ k,
                  float* __restrict__ out) {
    __shared__ short lds2[TR * 34 * 16];
    const int tid  = threadIdx.x;
    const int lane = tid & 63;
    const int wv   = tid >> 6;
    const int m    = lane & 15;
    const int g    = lane >> 4;
    int bid = blockIdx.x;
    int swz = (bid & 7) * 512 + (bid >> 3);
    int h0 = (swz >> 6) * 32;
    int w0 = (swz & 63) * 32;
    for (int p = tid; p < TR * 34; p += 256) {
        int r = p / 34, c = p - r * 34;
        int hh = h0 + r; if (hh > HIN - 1) hh = HIN - 1;
        int ww = w0 + c; if (ww > WIN - 1) ww = WIN - 1;
        const float* gp = x + hh * WIN + ww;
        short t[16];
        #pragma unroll
        for (int ci = 0; ci < 16; ++ci) t[ci] = f2bf(gp[ci * PLANE_IN]);
        bf16x8 lo, hi;
        #pragma unroll
        for (int j = 0; j < 8; ++j) { lo[j] = t[j]; hi[j] = t[8 + j]; }
        int sw = (c >> 2) & 1;
        bf16x8* dst = (bf16x8*)&lds2[p * 16];
        dst[sw] = lo; dst[1 - sw] = hi;
    }
    bf16x8 wf[5];
    #pragma unroll
    for (int i = 0; i < 5; ++i)
        #pragma unroll
        for (int j = 0; j < 8; ++j) {
            int kk = 32 * i + 8 * g + j;
            int tap = kk >> 4, ci = kk & 15;
            short v = 0;
            if (tap < 9) v = f2bf(k[(m * 16 + ci) * 9 + tap]);
            wf[i][j] = v;
        }
    int off[5];
    #pragma unroll
    for (int i = 0; i < 5; ++i) {
        int tap = 2 * i + (g >> 1);
        if (tap > 8) tap = 8;
        int kh = tap / 3, kw = tap - kh * 3;
        int col = m + kw;
        int o = (kh * 34 + col) * 32 + (g & 1) * 16;
        off[i] = o ^ ((col & 4) << 2);
    }
    __syncthreads();
    const char* ldsb = (const char*)lds2;
    const int coBase = g * 4;
    for (int hl8 = 0; hl8 < 8; ++hl8) {
        int hl = wv * 8 + hl8;
        int h = h0 + hl;
        bool hok = (h < HOUT);
        #pragma unroll
        for (int nh = 0; nh < 2; ++nh) {
            int wl = nh * 16;
            int tb = (hl * 34 + wl) * 32;
            f32x4 acc = {0.f, 0.f, 0.f, 0.f};
            #pragma unroll
            for (int i = 0; i < 5; ++i) {
                bf16x8 b = *(const bf16x8*)(ldsb + (tb + off[i]));
                acc = __builtin_amdgcn_mfma_f32_16x16x32_bf16(wf[i], b, acc, 0, 0, 0);
            }
            int w = w0 + wl + m;
            if (hok && w < WOUT) {
                float* op = out + h * WOUT + w;
                #pragma unroll
                for (int r = 0; r < 4; ++r)
                    op[(coBase + r) * PLANE_OUT] = acc[r];
            }
        }
    }
}

extern "C" void kernel_launch(void* const* d_in, const int* in_sizes, int n_in,
                              void* d_out, int out_size, void* d_ws, size_t ws_size,
                              hipStream_t stream) {
    const float* x = (const float*)d_in[0];
    const float* k = (const float*)d_in[1];
    float* out = (float*)d_out;
    if (ws_size >= WF_U32 * 4) {
        unsigned* wfbuf = (unsigned*)d_ws;
        wf_setup<<<dim3(1), dim3(64), 0, stream>>>(k, wfbuf);
        conv3x3_fused1k<<<dim3(4096), dim3(1024), 0, stream>>>(x, wfbuf, out);
    } else {
        conv3x3_mfma<<<dim3(4096), dim3(256), 0, stream>>>(x, k, out);
    }
}